// Round 1
// 22427.634 us; speedup vs baseline: 1.2480x; 1.2480x over previous
//
#include <hip/hip_runtime.h>
#include <stddef.h>

#define T_STEPS 1024
#define NBLK 128   // 64 WGs for layer 0, 64 WGs for layer 1; <=256 CUs -> co-resident

typedef __attribute__((ext_vector_type(8))) short bf16x8;
typedef __attribute__((ext_vector_type(4))) float f32x4;

// ws layout (bytes)
#define OFF_XB   ((size_t)0)                    // bf16 x   [64][1024][1024]
#define OFF_W    ((size_t)134217728)            // bf16 wts [wih0,whh0,wih1,whh1] each [1024][1024]
#define OFF_H0   (OFF_W + (size_t)8388608)      // bf16 h0 slots [2][64][1024]
#define OFF_H1   (OFF_H0 + (size_t)262144)      // bf16 h1 slots [2][64][1024]
#define OFF_B    (OFF_H1 + (size_t)262144)      // f32 bias [2][1024] (bih+bhh combined)
#define OFF_CTR  (OFF_B + (size_t)8192)         // int barrier counters: 8 x (32 ints = 128B apart)

__device__ __forceinline__ unsigned short f2bf(float f) {
  unsigned int u = __float_as_uint(f);
  u += 0x7fffu + ((u >> 16) & 1u);   // round-to-nearest-even
  return (unsigned short)(u >> 16);
}

// 16B of h-state via two native 8B agent-scope relaxed atomic loads.
// Agent scope -> sc1 -> bypasses the (non-cross-XCD-coherent) L2; served at the
// coherence point (MALL). No buffer_inv needed anywhere.
__device__ __forceinline__ bf16x8 ldh8(const unsigned short* p) {
  union { unsigned long long u[2]; bf16x8 v; } r;
  r.u[0] = __hip_atomic_load((const unsigned long long*)p,       __ATOMIC_RELAXED, __HIP_MEMORY_SCOPE_AGENT);
  r.u[1] = __hip_atomic_load((const unsigned long long*)(p + 4), __ATOMIC_RELAXED, __HIP_MEMORY_SCOPE_AGENT);
  return r.v;
}

__global__ void k_cvt_x(const float4* __restrict__ x4, ushort4* __restrict__ xb4) {
  size_t i = (size_t)blockIdx.x * blockDim.x + threadIdx.x;   // 16777216 float4s
  float4 v = x4[i];
  ushort4 o;
  o.x = f2bf(v.x); o.y = f2bf(v.y); o.z = f2bf(v.z); o.w = f2bf(v.w);
  xb4[i] = o;
}

__global__ void k_cvt_w(const float* __restrict__ Wih, const float* __restrict__ Whh,
                        ushort4* __restrict__ wt4) {
  size_t i4 = (size_t)blockIdx.x * blockDim.x + threadIdx.x;  // 1048576
  size_t e = i4 << 2;
  int arr = (int)(e >> 20);                  // 0:wih0 1:whh0 2:wih1 3:whh1
  size_t within = e & (size_t)1048575;
  const float* src = ((arr & 1) ? Whh : Wih) + ((arr >> 1) ? (size_t)1048576 : (size_t)0) + within;
  float4 v = *(const float4*)src;
  ushort4 o;
  o.x = f2bf(v.x); o.y = f2bf(v.y); o.z = f2bf(v.z); o.w = f2bf(v.w);
  wt4[i4] = o;
}

__global__ void k_init(const float* __restrict__ h0in, const float* __restrict__ bih,
                       const float* __restrict__ bhh,
                       unsigned short* __restrict__ h0s, unsigned short* __restrict__ h1s,
                       float* __restrict__ bias, int* __restrict__ ctr) {
  int tid = blockIdx.x * blockDim.x + threadIdx.x;  // 131072 = 64*2*1024
  int b = tid >> 11, rem = tid & 2047, l = rem >> 10, j = rem & 1023;
  float v = h0in[tid];                              // flat (b,l,j) == tid
  unsigned short* dst = l ? h1s : h0s;
  dst[(1 << 16) + (b << 10) + j] = f2bf(v);         // h_{-1} lives in slot 1
  if (tid < 2048) bias[tid] = bih[tid] + bhh[tid];
  if (tid < 256) ctr[tid] = 0;
}

// Persistent pipelined RNN.
// Phase p: layer-0 WGs (g=0) compute h0_p = tanh(x_p@Wih0^T + h0_{p-1}@Whh0^T + b0)
//          layer-1 WGs (g=1) compute h1_{p-1} = tanh(h0_{p-1}@Wih1^T + h1_{p-2}@Whh1^T + b1)
// Both read only phase-(p-1) results -> one grid barrier per phase.
// Slots: h0_p -> p&1 ; h1_{p-1} -> (p+1)&1.
// Coherence protocol: h-state moves via agent-scope relaxed atomics (sc1, write-through
// to / read from the coherence point). NO threadfence / cache maintenance anywhere.
// Release = s_waitcnt vmcnt(0) before arrival; acquire = loads already bypass caches.
__global__ __launch_bounds__(128) void k_rnn(
    const unsigned short* __restrict__ xb,
    const unsigned short* __restrict__ wts,
    unsigned short* __restrict__ h0s,
    unsigned short* __restrict__ h1s,
    const float* __restrict__ bias,
    int* ctr,
    float* __restrict__ out)
{
  // 16 cols x K=2048 of bf16 weights, fragment-linear: chunk (kc=k/8, c) at 16B offset (kc*16+c)*16
  __shared__ __align__(16) unsigned short wlds[32768];   // exactly 64 KB

  const int wg = blockIdx.x;
  const int g = wg >> 6;                 // 0: layer0, 1: layer1
  const int cbase = (wg & 63) << 4;      // 16 output columns per WG
  const int tid = threadIdx.x;
  const int lane = tid & 63;
  const int wave = tid >> 6;             // 2 waves/WG; each wave: 2 row-tiles (32 rows)

  {  // preload weight slice into LDS (once)
    const unsigned short* wa = wts + ((size_t)(g * 2) << 20);       // K 0..1023
    const unsigned short* wb = wts + ((size_t)(g * 2 + 1) << 20);   // K 1024..2047
    for (int i = 0; i < 32; ++i) {
      int chunk = i * 128 + tid;         // 4096 chunks of 16B
      int kc = chunk >> 4, c = chunk & 15;
      int k = kc << 3;
      const unsigned short* s = (k < 1024)
          ? (wa + (((size_t)(cbase + c)) << 10) + k)
          : (wb + (((size_t)(cbase + c)) << 10) + (k - 1024));
      *(int4*)(&wlds[(size_t)chunk * 8]) = *(const int4*)s;
    }
  }
  __syncthreads();

  const int am = lane & 15;              // A row within tile / C col
  const int akk = (lane >> 4) << 3;      // A k-offset within 32-chunk
  const int arow0 = (wave << 5) + am;    // tile0 A row; tile1 = +16
  const float biasv = bias[(g << 10) + cbase + am];
  const int ccol = cbase + am;
  const int crow0 = (wave << 5) + ((lane >> 4) << 2);

  float* __restrict__ hfin = out + (size_t)67108864;

  for (int p = 0; p <= T_STEPS; ++p) {
    f32x4 acc0 = {0.f, 0.f, 0.f, 0.f};
    f32x4 acc1 = {0.f, 0.f, 0.f, 0.f};
    const bool active = (g == 0) ? (p < T_STEPS) : (p >= 1);
    const int t = (g == 0) ? p : (p - 1);

    // x-projection: no cross-phase dependency -> runs BEFORE the barrier wait
    if (g == 0 && active) {
      const unsigned short* a0p = xb + (((size_t)arow0 * T_STEPS + t) << 10) + akk;
      const unsigned short* a1p = xb + (((size_t)(arow0 + 16) * T_STEPS + t) << 10) + akk;
      #pragma unroll 8
      for (int k0 = 0; k0 < 1024; k0 += 32) {
        bf16x8 b  = *(const bf16x8*)(&wlds[k0 * 16 + lane * 8]);
        bf16x8 a0 = *(const bf16x8*)(a0p + k0);
        bf16x8 a1 = *(const bf16x8*)(a1p + k0);
        acc0 = __builtin_amdgcn_mfma_f32_16x16x32_bf16(a0, b, acc0, 0, 0, 0);
        acc1 = __builtin_amdgcn_mfma_f32_16x16x32_bf16(a1, b, acc1, 0, 0, 0);
      }
    }

    if (p > 0) {
      // 8-way spread barrier wait: tids 0..7 each poll one counter line in parallel.
      if (tid < 8) {
        const int tgt = p << 4;   // 16 arrivals per sub-counter per phase
        while (__hip_atomic_load(&ctr[tid << 5], __ATOMIC_RELAXED, __HIP_MEMORY_SCOPE_AGENT) < tgt)
          __builtin_amdgcn_s_sleep(2);
      }
      __syncthreads();
      // no acquire fence needed: h loads below bypass L1/L2 (agent-scope atomics)
    }

    if (active) {
      if (g == 1) {  // layer1 first half: h0_{p-1} @ Wih1^T
        const unsigned short* hsrc = h0s + (((size_t)(t & 1)) << 16);
        const unsigned short* a0p = hsrc + (((size_t)arow0) << 10) + akk;
        #pragma unroll 8
        for (int k0 = 0; k0 < 1024; k0 += 32) {
          bf16x8 b  = *(const bf16x8*)(&wlds[k0 * 16 + lane * 8]);
          bf16x8 a0 = ldh8(a0p + k0);
          bf16x8 a1 = ldh8(a0p + (16 << 10) + k0);
          acc0 = __builtin_amdgcn_mfma_f32_16x16x32_bf16(a0, b, acc0, 0, 0, 0);
          acc1 = __builtin_amdgcn_mfma_f32_16x16x32_bf16(a1, b, acc1, 0, 0, 0);
        }
      }
      {  // recurrent half: h_{prev} @ Whh^T  (K 1024..2047 in LDS)
        const unsigned short* hsrc = (g == 0)
            ? (h0s + (((size_t)((p + 1) & 1)) << 16))    // h0_{p-1}
            : (h1s + (((size_t)(p & 1)) << 16));         // h1_{p-2}
        const unsigned short* a0p = hsrc + (((size_t)arow0) << 10) + akk;
        #pragma unroll 8
        for (int k0 = 0; k0 < 1024; k0 += 32) {
          bf16x8 b  = *(const bf16x8*)(&wlds[(k0 + 1024) * 16 + lane * 8]);
          bf16x8 a0 = ldh8(a0p + k0);
          bf16x8 a1 = ldh8(a0p + (16 << 10) + k0);
          acc0 = __builtin_amdgcn_mfma_f32_16x16x32_bf16(a0, b, acc0, 0, 0, 0);
          acc1 = __builtin_amdgcn_mfma_f32_16x16x32_bf16(a1, b, acc1, 0, 0, 0);
        }
      }

      unsigned short* hdst = (g == 0)
          ? (h0s + (((size_t)(p & 1)) << 16))
          : (h1s + (((size_t)((p + 1) & 1)) << 16));
      #pragma unroll
      for (int i = 0; i < 4; ++i) {
        const int r0 = crow0 + i;
        const int r1 = crow0 + 16 + i;
        const float v0 = tanhf(acc0[i] + biasv);
        const float v1 = tanhf(acc1[i] + biasv);
        // lane pair (2c, 2c+1) holds adjacent output cols of the same rows:
        // pack two bf16 into one uint -> native 4B agent-scope atomic store
        const float w0 = __shfl_xor(v0, 1);
        const float w1 = __shfl_xor(v1, 1);
        if (!(lane & 1)) {
          unsigned int p0 = (unsigned int)f2bf(v0) | ((unsigned int)f2bf(w0) << 16);
          unsigned int p1 = (unsigned int)f2bf(v1) | ((unsigned int)f2bf(w1) << 16);
          __hip_atomic_store((unsigned int*)(hdst + (((size_t)r0) << 10) + ccol), p0,
                             __ATOMIC_RELAXED, __HIP_MEMORY_SCOPE_AGENT);
          __hip_atomic_store((unsigned int*)(hdst + (((size_t)r1) << 10) + ccol), p1,
                             __ATOMIC_RELAXED, __HIP_MEMORY_SCOPE_AGENT);
        }
        if (g == 1) {
          __builtin_nontemporal_store(v0, &out[((((size_t)t << 6) + r0) << 10) + ccol]);
          __builtin_nontemporal_store(v1, &out[((((size_t)t << 6) + r1) << 10) + ccol]);
        }
        if (t == T_STEPS - 1) {
          hfin[((size_t)(r0 * 2 + g) << 10) + ccol] = v0;
          hfin[((size_t)(r1 * 2 + g) << 10) + ccol] = v1;
        }
      }
    }

    // Release: sc1 stores are at the coherence point once vmcnt retires.
    asm volatile("s_waitcnt vmcnt(0)" ::: "memory");
    __syncthreads();      // all waves of this WG drained before arrival
    if (tid == 0)
      __hip_atomic_fetch_add(&ctr[(wg & 7) << 5], 1, __ATOMIC_RELAXED, __HIP_MEMORY_SCOPE_AGENT);
  }
}

extern "C" void kernel_launch(void* const* d_in, const int* in_sizes, int n_in,
                              void* d_out, int out_size, void* d_ws, size_t ws_size,
                              hipStream_t stream) {
  (void)in_sizes; (void)n_in; (void)out_size; (void)ws_size;
  const float* x   = (const float*)d_in[0];
  const float* h0  = (const float*)d_in[1];
  const float* Wih = (const float*)d_in[2];
  const float* bih = (const float*)d_in[3];
  const float* Whh = (const float*)d_in[4];
  const float* bhh = (const float*)d_in[5];
  float* out = (float*)d_out;
  char* ws = (char*)d_ws;

  unsigned short* xb  = (unsigned short*)(ws + OFF_XB);
  unsigned short* wts = (unsigned short*)(ws + OFF_W);
  unsigned short* h0s = (unsigned short*)(ws + OFF_H0);
  unsigned short* h1s = (unsigned short*)(ws + OFF_H1);
  float* bias = (float*)(ws + OFF_B);
  int* ctr = (int*)(ws + OFF_CTR);

  k_cvt_x<<<65536, 256, 0, stream>>>((const float4*)x, (ushort4*)xb);
  k_cvt_w<<<4096, 256, 0, stream>>>(Wih, Whh, (ushort4*)wts);
  k_init<<<512, 256, 0, stream>>>(h0, bih, bhh, h0s, h1s, bias, ctr);
  k_rnn<<<NBLK, 128, 0, stream>>>(xb, wts, h0s, h1s, bias, ctr, out);
}

// Round 2
// 16987.483 us; speedup vs baseline: 1.6476x; 1.3202x over previous
//
#include <hip/hip_runtime.h>
#include <stddef.h>

#define T_STEPS 1024
#define NBLK 128   // 64 WGs layer0 + 64 WGs layer1, 256 threads each

typedef __attribute__((ext_vector_type(8))) short bf16x8;
typedef __attribute__((ext_vector_type(4))) float f32x4;

// ws layout (bytes)
#define OFF_XB   ((size_t)0)                    // bf16 x, TRANSPOSED [t][b][in] = [1024][64][1024]
#define OFF_W    ((size_t)134217728)            // bf16 wts [wih0,whh0,wih1,whh1] each [1024][1024]
#define OFF_H0   (OFF_W + (size_t)8388608)      // bf16 h0, 4 slots x [64][1024]  (524288 B)
#define OFF_H1   (OFF_H0 + (size_t)524288)      // bf16 h1, 2 slots x [64][1024]  (262144 B)
#define OFF_B    (OFF_H1 + (size_t)262144)      // f32 bias [2][1024] (bih+bhh combined)
#define OFF_CTR  (OFF_B + (size_t)8192)         // 2048 ints: ctr0 lines at [i*32], ctr1 at [1024+i*32]

__device__ __forceinline__ unsigned short f2bf(float f) {
  unsigned int u = __float_as_uint(f);
  u += 0x7fffu + ((u >> 16) & 1u);   // round-to-nearest-even
  return (unsigned short)(u >> 16);
}

// 16B of h-state via two native 8B agent-scope relaxed atomic loads (sc1: bypasses
// non-coherent L1/L2, served at the coherence point). No cache maintenance needed.
__device__ __forceinline__ bf16x8 ldh8(const unsigned short* p) {
  union { unsigned long long u[2]; bf16x8 v; } r;
  r.u[0] = __hip_atomic_load((const unsigned long long*)p,       __ATOMIC_RELAXED, __HIP_MEMORY_SCOPE_AGENT);
  r.u[1] = __hip_atomic_load((const unsigned long long*)(p + 4), __ATOMIC_RELAXED, __HIP_MEMORY_SCOPE_AGENT);
  return r.v;
}

__device__ __forceinline__ void waitline(int* p, int tgt) {
  while (__hip_atomic_load(p, __ATOMIC_RELAXED, __HIP_MEMORY_SCOPE_AGENT) < tgt)
    __builtin_amdgcn_s_sleep(1);
}

// x: [b][t][in] f32  ->  xb: [t][b][in] bf16 (contiguous 128KB slab per timestep)
__global__ void k_cvt_x(const float4* __restrict__ x4, ushort4* __restrict__ xb4) {
  size_t i = (size_t)blockIdx.x * blockDim.x + threadIdx.x;   // 16777216 float4s
  int b = (int)(i >> 18);
  int rem = (int)(i & 262143);
  int t = rem >> 8, c = rem & 255;
  float4 v = x4[i];
  ushort4 o;
  o.x = f2bf(v.x); o.y = f2bf(v.y); o.z = f2bf(v.z); o.w = f2bf(v.w);
  xb4[((size_t)t << 14) + ((size_t)b << 8) + c] = o;
}

__global__ void k_cvt_w(const float* __restrict__ Wih, const float* __restrict__ Whh,
                        ushort4* __restrict__ wt4) {
  size_t i4 = (size_t)blockIdx.x * blockDim.x + threadIdx.x;  // 1048576
  size_t e = i4 << 2;
  int arr = (int)(e >> 20);                  // 0:wih0 1:whh0 2:wih1 3:whh1
  size_t within = e & (size_t)1048575;
  const float* src = ((arr & 1) ? Whh : Wih) + ((arr >> 1) ? (size_t)1048576 : (size_t)0) + within;
  float4 v = *(const float4*)src;
  ushort4 o;
  o.x = f2bf(v.x); o.y = f2bf(v.y); o.z = f2bf(v.z); o.w = f2bf(v.w);
  wt4[i4] = o;
}

__global__ void k_init(const float* __restrict__ h0in, const float* __restrict__ bih,
                       const float* __restrict__ bhh,
                       unsigned short* __restrict__ h0s, unsigned short* __restrict__ h1s,
                       float* __restrict__ bias, int* __restrict__ ctr) {
  int tid = blockIdx.x * blockDim.x + threadIdx.x;  // 131072 = 64*2*1024
  int b = tid >> 11, rem = tid & 2047, l = rem >> 10, j = rem & 1023;
  float v = h0in[tid];                              // flat (b,l,j) == tid
  if (l == 0) h0s[(3 << 16) + (b << 10) + j] = f2bf(v);   // h0_{-1} -> slot 3 (of 4)
  else        h1s[(1 << 16) + (b << 10) + j] = f2bf(v);   // h1_{-1} -> slot 1 (of 2)
  if (tid < 2048) bias[tid] = bih[tid] + bhh[tid];
  if (tid < 2048) ctr[tid] = 0;
}

// Decoupled-clock persistent RNN.
// Layer 0 (WGs 0..63):  step t needs h0_{t-1}  [ctr0 >= 64t]  and h0-slot WAR
//                       protection [ctr1 >= 64(t-3), slot depth 4].
// Layer 1 (WGs 64..127): step u needs h0_u [ctr0 >= 64(u+1)] for the Wih1 half,
//                       then h1_{u-1} [ctr1 >= 64u] for the Whh1 half. It trails
//                       layer 0 by ~1 phase, so its first wait is pre-satisfied and
//                       the Wih1 matmul overlaps its own recurrence wait.
// All h traffic via agent-scope relaxed atomics (no fences); release = vmcnt(0).
__global__ __launch_bounds__(256) void k_rnn(
    const unsigned short* __restrict__ xb,
    const unsigned short* __restrict__ wts,
    unsigned short* __restrict__ h0s,
    unsigned short* __restrict__ h1s,
    const float* __restrict__ bias,
    int* ctr,
    float* __restrict__ out)
{
  // 16 cols x K=2048 bf16 weights, fragment-linear: chunk (kc, c) at 16B offset (kc*16+c)*16
  __shared__ __align__(16) unsigned short wlds[32768];   // 64 KB

  const int wg = blockIdx.x;
  const int g = wg >> 6;                 // 0: layer0, 1: layer1
  const int cbase = (wg & 63) << 4;      // 16 output columns per WG
  const int tid = threadIdx.x;
  const int lane = tid & 63;
  const int wave = tid >> 6;             // 4 waves; each owns 16 batch rows

  {  // preload weight slice into LDS (once): 4096 16B chunks / 256 threads
    const unsigned short* wa = wts + ((size_t)(g * 2) << 20);       // K 0..1023   (Wih)
    const unsigned short* wb = wts + ((size_t)(g * 2 + 1) << 20);   // K 1024..2047 (Whh)
    for (int i = 0; i < 16; ++i) {
      int chunk = i * 256 + tid;
      int kc = chunk >> 4, c = chunk & 15;
      int k = kc << 3;
      const unsigned short* s = (k < 1024)
          ? (wa + (((size_t)(cbase + c)) << 10) + k)
          : (wb + (((size_t)(cbase + c)) << 10) + (k - 1024));
      *(int4*)(&wlds[(size_t)chunk * 8]) = *(const int4*)s;
    }
  }
  __syncthreads();

  const int am = lane & 15;              // A row within tile / C col
  const int akk = (lane >> 4) << 3;      // A k-offset within 32-chunk
  const int arow = (wave << 4) + am;     // batch row for A fragments
  const float biasv = bias[(g << 10) + cbase + am];
  const int ccol = cbase + am;
  const int crow = (wave << 4) + ((lane >> 4) << 2);

  int* ctr0 = ctr;
  int* ctr1 = ctr + 1024;
  float* __restrict__ hfin = out + (size_t)67108864;

  if (g == 0) {
    for (int t = 0; t < T_STEPS; ++t) {
      // wait: h0_{t-1} visible (ctr0) and slot t&3 free of layer-1 readers (ctr1)
      if (tid < 16) {
        int idx = tid & 7;
        int* p   = (tid < 8) ? (ctr0 + (idx << 5)) : (ctr1 + (idx << 5));
        int tgt  = (tid < 8) ? (t * 8) : ((t - 3) * 8);
        waitline(p, tgt);
      }
      __syncthreads();

      f32x4 aX = {0.f, 0.f, 0.f, 0.f};
      f32x4 aH = {0.f, 0.f, 0.f, 0.f};
      const unsigned short* xp = xb + ((size_t)t << 16) + ((size_t)arow << 10) + akk;
      const unsigned short* hp = h0s + (((size_t)((t + 3) & 3)) << 16) + ((size_t)arow << 10) + akk;
      #pragma unroll 8
      for (int k0 = 0; k0 < 1024; k0 += 32) {
        bf16x8 bx = *(const bf16x8*)(&wlds[k0 * 16 + lane * 8]);
        bf16x8 bh = *(const bf16x8*)(&wlds[(k0 + 1024) * 16 + lane * 8]);
        bf16x8 ax = *(const bf16x8*)(xp + k0);           // cached load (L2-resident slab)
        bf16x8 ah = ldh8(hp + k0);                       // uncached (coherence point)
        aX = __builtin_amdgcn_mfma_f32_16x16x32_bf16(ax, bx, aX, 0, 0, 0);
        aH = __builtin_amdgcn_mfma_f32_16x16x32_bf16(ah, bh, aH, 0, 0, 0);
      }

      unsigned short* hdst = h0s + (((size_t)(t & 3)) << 16);
      #pragma unroll
      for (int i = 0; i < 4; ++i) {
        const int r = crow + i;
        const float v = tanhf(aX[i] + aH[i] + biasv);
        const float w = __shfl_xor(v, 1);
        if (!(lane & 1)) {
          unsigned int pk = (unsigned int)f2bf(v) | ((unsigned int)f2bf(w) << 16);
          __hip_atomic_store((unsigned int*)(hdst + (((size_t)r) << 10) + ccol), pk,
                             __ATOMIC_RELAXED, __HIP_MEMORY_SCOPE_AGENT);
        }
        if (t == T_STEPS - 1) hfin[((size_t)(r * 2 + 0) << 10) + ccol] = v;
      }

      asm volatile("s_waitcnt vmcnt(0)" ::: "memory");
      __syncthreads();
      if (tid == 0)
        __hip_atomic_fetch_add(&ctr0[(wg & 7) << 5], 1, __ATOMIC_RELAXED, __HIP_MEMORY_SCOPE_AGENT);
    }
  } else {
    for (int u = 0; u < T_STEPS; ++u) {
      // stage 1: h0_u visible (usually pre-satisfied since we trail layer 0)
      if (tid < 8) waitline(ctr0 + (tid << 5), (u + 1) * 8);
      __syncthreads();

      f32x4 aX = {0.f, 0.f, 0.f, 0.f};
      {
        const unsigned short* h0p = h0s + (((size_t)(u & 3)) << 16) + ((size_t)arow << 10) + akk;
        #pragma unroll 8
        for (int k0 = 0; k0 < 1024; k0 += 32) {
          bf16x8 bx = *(const bf16x8*)(&wlds[k0 * 16 + lane * 8]);
          bf16x8 a0 = ldh8(h0p + k0);
          aX = __builtin_amdgcn_mfma_f32_16x16x32_bf16(a0, bx, aX, 0, 0, 0);
        }
      }

      // stage 2: own recurrence h1_{u-1}
      if (tid < 8) waitline(ctr1 + (tid << 5), u * 8);
      __syncthreads();

      f32x4 aH = {0.f, 0.f, 0.f, 0.f};
      {
        const unsigned short* h1p = h1s + (((size_t)((u + 1) & 1)) << 16) + ((size_t)arow << 10) + akk;
        #pragma unroll 8
        for (int k0 = 0; k0 < 1024; k0 += 32) {
          bf16x8 bh = *(const bf16x8*)(&wlds[(k0 + 1024) * 16 + lane * 8]);
          bf16x8 a1 = ldh8(h1p + k0);
          aH = __builtin_amdgcn_mfma_f32_16x16x32_bf16(a1, bh, aH, 0, 0, 0);
        }
      }

      unsigned short* hdst = h1s + (((size_t)(u & 1)) << 16);
      #pragma unroll
      for (int i = 0; i < 4; ++i) {
        const int r = crow + i;
        const float v = tanhf(aX[i] + aH[i] + biasv);
        const float w = __shfl_xor(v, 1);
        if (!(lane & 1)) {
          unsigned int pk = (unsigned int)f2bf(v) | ((unsigned int)f2bf(w) << 16);
          __hip_atomic_store((unsigned int*)(hdst + (((size_t)r) << 10) + ccol), pk,
                             __ATOMIC_RELAXED, __HIP_MEMORY_SCOPE_AGENT);
        }
        __builtin_nontemporal_store(v, &out[((((size_t)u << 6) + r) << 10) + ccol]);
        if (u == T_STEPS - 1) hfin[((size_t)(r * 2 + 1) << 10) + ccol] = v;
      }

      asm volatile("s_waitcnt vmcnt(0)" ::: "memory");
      __syncthreads();
      if (tid == 0)
        __hip_atomic_fetch_add(&ctr1[(wg & 7) << 5], 1, __ATOMIC_RELAXED, __HIP_MEMORY_SCOPE_AGENT);
    }
  }
}

extern "C" void kernel_launch(void* const* d_in, const int* in_sizes, int n_in,
                              void* d_out, int out_size, void* d_ws, size_t ws_size,
                              hipStream_t stream) {
  (void)in_sizes; (void)n_in; (void)out_size; (void)ws_size;
  const float* x   = (const float*)d_in[0];
  const float* h0  = (const float*)d_in[1];
  const float* Wih = (const float*)d_in[2];
  const float* bih = (const float*)d_in[3];
  const float* Whh = (const float*)d_in[4];
  const float* bhh = (const float*)d_in[5];
  float* out = (float*)d_out;
  char* ws = (char*)d_ws;

  unsigned short* xb  = (unsigned short*)(ws + OFF_XB);
  unsigned short* wts = (unsigned short*)(ws + OFF_W);
  unsigned short* h0s = (unsigned short*)(ws + OFF_H0);
  unsigned short* h1s = (unsigned short*)(ws + OFF_H1);
  float* bias = (float*)(ws + OFF_B);
  int* ctr = (int*)(ws + OFF_CTR);

  k_cvt_x<<<65536, 256, 0, stream>>>((const float4*)x, (ushort4*)xb);
  k_cvt_w<<<4096, 256, 0, stream>>>(Wih, Whh, (ushort4*)wts);
  k_init<<<512, 256, 0, stream>>>(h0, bih, bhh, h0s, h1s, bias, ctr);
  k_rnn<<<NBLK, 256, 0, stream>>>(xb, wts, h0s, h1s, bias, ctr, out);
}

// Round 3
// 10504.523 us; speedup vs baseline: 2.6645x; 1.6172x over previous
//
#include <hip/hip_runtime.h>
#include <stddef.h>

#define T_STEPS 1024
#define NBLK 128   // 64 WGs layer0 + 64 WGs layer1, 256 threads each

typedef __attribute__((ext_vector_type(8))) short bf16x8;
typedef __attribute__((ext_vector_type(4))) float f32x4;

// ws layout (bytes)
#define OFF_XB   ((size_t)0)                    // bf16 x, TRANSPOSED [t][b][in] = [1024][64][1024]
#define OFF_W    ((size_t)134217728)            // bf16 wts [wih0,whh0,wih1,whh1] each [1024][1024]
#define OFF_H0   (OFF_W + (size_t)8388608)      // bf16 h0, 4 slots x [64][1024]  (524288 B)
#define OFF_H1   (OFF_H0 + (size_t)524288)      // bf16 h1, 2 slots x [64][1024]  (262144 B)
#define OFF_B    (OFF_H1 + (size_t)262144)      // f32 bias [2][1024] (bih+bhh combined)
#define OFF_CTR  (OFF_B + (size_t)8192)         // 2048 ints: ctr0 lines at [i*32], ctr1 at [1024+i*32]

__device__ __forceinline__ unsigned short f2bf(float f) {
  unsigned int u = __float_as_uint(f);
  u += 0x7fffu + ((u >> 16) & 1u);   // round-to-nearest-even
  return (unsigned short)(u >> 16);
}

__device__ __forceinline__ void waitline(int* p, int tgt) {
  while (__hip_atomic_load(p, __ATOMIC_RELAXED, __HIP_MEMORY_SCOPE_AGENT) < tgt)
    __builtin_amdgcn_s_sleep(1);
}

// 16B cache-bypassing load (sc0 sc1 -> served at the coherence point; no stale
// L1/L2 hits possible). Pipelined manually with counted vmcnt waits below.
#define GLD16(dst, addr) \
  asm volatile("global_load_dwordx4 %0, %1, off sc0 sc1" : "=v"(dst) : "v"(addr))

// x: [b][t][in] f32  ->  xb: [t][b][in] bf16 (contiguous 128KB slab per timestep)
__global__ void k_cvt_x(const float4* __restrict__ x4, ushort4* __restrict__ xb4) {
  size_t i = (size_t)blockIdx.x * blockDim.x + threadIdx.x;   // 16777216 float4s
  int b = (int)(i >> 18);
  int rem = (int)(i & 262143);
  int t = rem >> 8, c = rem & 255;
  float4 v = x4[i];
  ushort4 o;
  o.x = f2bf(v.x); o.y = f2bf(v.y); o.z = f2bf(v.z); o.w = f2bf(v.w);
  xb4[((size_t)t << 14) + ((size_t)b << 8) + c] = o;
}

__global__ void k_cvt_w(const float* __restrict__ Wih, const float* __restrict__ Whh,
                        ushort4* __restrict__ wt4) {
  size_t i4 = (size_t)blockIdx.x * blockDim.x + threadIdx.x;  // 1048576
  size_t e = i4 << 2;
  int arr = (int)(e >> 20);                  // 0:wih0 1:whh0 2:wih1 3:whh1
  size_t within = e & (size_t)1048575;
  const float* src = ((arr & 1) ? Whh : Wih) + ((arr >> 1) ? (size_t)1048576 : (size_t)0) + within;
  float4 v = *(const float4*)src;
  ushort4 o;
  o.x = f2bf(v.x); o.y = f2bf(v.y); o.z = f2bf(v.z); o.w = f2bf(v.w);
  wt4[i4] = o;
}

__global__ void k_init(const float* __restrict__ h0in, const float* __restrict__ bih,
                       const float* __restrict__ bhh,
                       unsigned short* __restrict__ h0s, unsigned short* __restrict__ h1s,
                       float* __restrict__ bias, int* __restrict__ ctr) {
  int tid = blockIdx.x * blockDim.x + threadIdx.x;  // 131072 = 64*2*1024
  int b = tid >> 11, rem = tid & 2047, l = rem >> 10, j = rem & 1023;
  float v = h0in[tid];                              // flat (b,l,j) == tid
  if (l == 0) h0s[(3 << 16) + (b << 10) + j] = f2bf(v);   // h0_{-1} -> slot 3 (of 4)
  else        h1s[(1 << 16) + (b << 10) + j] = f2bf(v);   // h1_{-1} -> slot 1 (of 2)
  if (tid < 2048) bias[tid] = bih[tid] + bhh[tid];
  if (tid < 2048) ctr[tid] = 0;
}

// Decoupled-clock persistent RNN (round-2 protocol) with manually software-
// pipelined cache-bypassing h loads (depth-8 rotating register file, counted
// vmcnt waits; ordering enforced by "+v" dataflow on the waitcnt asm).
__global__ __launch_bounds__(256) void k_rnn(
    const unsigned short* __restrict__ xb,
    const unsigned short* __restrict__ wts,
    unsigned short* __restrict__ h0s,
    unsigned short* __restrict__ h1s,
    const float* __restrict__ bias,
    int* ctr,
    float* __restrict__ out)
{
  __shared__ __align__(16) unsigned short wlds[32768];   // 64 KB weight slice

  const int wg = blockIdx.x;
  const int g = wg >> 6;                 // 0: layer0, 1: layer1
  const int cbase = (wg & 63) << 4;      // 16 output columns per WG
  const int tid = threadIdx.x;
  const int lane = tid & 63;
  const int wave = tid >> 6;             // 4 waves; each owns 16 batch rows

  {  // preload weight slice into LDS (once): 4096 16B chunks / 256 threads
    const unsigned short* wa = wts + ((size_t)(g * 2) << 20);       // K 0..1023   (Wih)
    const unsigned short* wb = wts + ((size_t)(g * 2 + 1) << 20);   // K 1024..2047 (Whh)
    for (int i = 0; i < 16; ++i) {
      int chunk = i * 256 + tid;
      int kc = chunk >> 4, c = chunk & 15;
      int k = kc << 3;
      const unsigned short* s = (k < 1024)
          ? (wa + (((size_t)(cbase + c)) << 10) + k)
          : (wb + (((size_t)(cbase + c)) << 10) + (k - 1024));
      *(int4*)(&wlds[(size_t)chunk * 8]) = *(const int4*)s;
    }
  }
  __syncthreads();

  const int am = lane & 15;              // A row within tile / C col
  const int akk = (lane >> 4) << 3;      // A k-offset within 32-chunk
  const int arow = (wave << 4) + am;     // batch row for A fragments
  const float biasv = bias[(g << 10) + cbase + am];
  const int ccol = cbase + am;
  const int crow = (wave << 4) + ((lane >> 4) << 2);

  int* ctr0 = ctr;
  int* ctr1 = ctr + 1024;
  float* __restrict__ hfin = out + (size_t)67108864;

  if (g == 0) {
    for (int t = 0; t < T_STEPS; ++t) {
      // x-projection BEFORE the wait (no cross-phase dependency)
      f32x4 aX = {0.f, 0.f, 0.f, 0.f};
      {
        const unsigned short* xp = xb + ((size_t)t << 16) + ((size_t)arow << 10) + akk;
        #pragma unroll 8
        for (int k0 = 0; k0 < 1024; k0 += 32) {
          bf16x8 bx = *(const bf16x8*)(&wlds[k0 * 16 + lane * 8]);
          bf16x8 ax = *(const bf16x8*)(xp + k0);   // cached (L2/L3-resident slab)
          aX = __builtin_amdgcn_mfma_f32_16x16x32_bf16(ax, bx, aX, 0, 0, 0);
        }
      }

      // wait: h0_{t-1} visible (ctr0 >= 8t per line) and slot WAR-free (ctr1 >= 8(t-3))
      if (tid < 16) {
        int idx = tid & 7;
        int* p  = (tid < 8) ? (ctr0 + (idx << 5)) : (ctr1 + (idx << 5));
        int tgt = (tid < 8) ? (t * 8) : ((t - 3) * 8);
        waitline(p, tgt);
      }
      __syncthreads();

      // recurrent half: h0_{t-1} @ Whh0^T, manual pipeline depth 8
      f32x4 aH = {0.f, 0.f, 0.f, 0.f};
      {
        const unsigned short* hp = h0s + (((size_t)((t + 3) & 3)) << 16) + ((size_t)arow << 10) + akk;
        bf16x8 q0, q1, q2, q3, q4, q5, q6, q7;
        GLD16(q0, hp + 0 * 32); GLD16(q1, hp + 1 * 32); GLD16(q2, hp + 2 * 32); GLD16(q3, hp + 3 * 32);
        GLD16(q4, hp + 4 * 32); GLD16(q5, hp + 5 * 32); GLD16(q6, hp + 6 * 32); GLD16(q7, hp + 7 * 32);
#define L0W(j, s, wn) \
        { asm volatile("s_waitcnt vmcnt(" #wn ")" : "+v"(q##s)); \
          bf16x8 bh = *(const bf16x8*)(&wlds[((j) * 32 + 1024) * 16 + lane * 8]); \
          aH = __builtin_amdgcn_mfma_f32_16x16x32_bf16(q##s, bh, aH, 0, 0, 0); }
#define L0WI(j, s) \
        { asm volatile("s_waitcnt vmcnt(7)" : "+v"(q##s)); \
          bf16x8 bh = *(const bf16x8*)(&wlds[((j) * 32 + 1024) * 16 + lane * 8]); \
          aH = __builtin_amdgcn_mfma_f32_16x16x32_bf16(q##s, bh, aH, 0, 0, 0); \
          GLD16(q##s, hp + ((j) + 8) * 32); }
        L0WI(0,0) L0WI(1,1) L0WI(2,2) L0WI(3,3) L0WI(4,4) L0WI(5,5) L0WI(6,6) L0WI(7,7)
        L0WI(8,0) L0WI(9,1) L0WI(10,2) L0WI(11,3) L0WI(12,4) L0WI(13,5) L0WI(14,6) L0WI(15,7)
        L0WI(16,0) L0WI(17,1) L0WI(18,2) L0WI(19,3) L0WI(20,4) L0WI(21,5) L0WI(22,6) L0WI(23,7)
        L0W(24,0,7) L0W(25,1,6) L0W(26,2,5) L0W(27,3,4)
        L0W(28,4,3) L0W(29,5,2) L0W(30,6,1) L0W(31,7,0)
#undef L0W
#undef L0WI
      }

      unsigned short* hdst = h0s + (((size_t)(t & 3)) << 16);
      #pragma unroll
      for (int i = 0; i < 4; ++i) {
        const int r = crow + i;
        const float v = tanhf(aX[i] + aH[i] + biasv);
        const float w = __shfl_xor(v, 1);
        if (!(lane & 1)) {
          unsigned int pk = (unsigned int)f2bf(v) | ((unsigned int)f2bf(w) << 16);
          __hip_atomic_store((unsigned int*)(hdst + (((size_t)r) << 10) + ccol), pk,
                             __ATOMIC_RELAXED, __HIP_MEMORY_SCOPE_AGENT);
        }
        if (t == T_STEPS - 1) hfin[((size_t)(r * 2 + 0) << 10) + ccol] = v;
      }

      asm volatile("s_waitcnt vmcnt(0)" ::: "memory");
      __syncthreads();
      if (tid == 0)
        __hip_atomic_fetch_add(&ctr0[(wg & 7) << 5], 1, __ATOMIC_RELAXED, __HIP_MEMORY_SCOPE_AGENT);
    }
  } else {
    for (int u = 0; u < T_STEPS; ++u) {
      // combined wait: h0_u visible (ctr0 >= 8(u+1)) and h1_{u-1} visible (ctr1 >= 8u)
      if (tid < 16) {
        int idx = tid & 7;
        int* p  = (tid < 8) ? (ctr0 + (idx << 5)) : (ctr1 + (idx << 5));
        int tgt = (tid < 8) ? ((u + 1) * 8) : (u * 8);
        waitline(p, tgt);
      }
      __syncthreads();

      // fused: h0_u @ Wih1^T  +  h1_{u-1} @ Whh1^T, two interleaved streams, depth 8 pairs
      f32x4 aX = {0.f, 0.f, 0.f, 0.f};
      f32x4 aH = {0.f, 0.f, 0.f, 0.f};
      {
        const unsigned short* h0p = h0s + (((size_t)(u & 3)) << 16) + ((size_t)arow << 10) + akk;
        const unsigned short* h1p = h1s + (((size_t)((u + 1) & 1)) << 16) + ((size_t)arow << 10) + akk;
        bf16x8 e0, e1, e2, e3, e4, e5, e6, e7;
        bf16x8 r0, r1, r2, r3, r4, r5, r6, r7;
        GLD16(e0, h0p + 0 * 32); GLD16(r0, h1p + 0 * 32);
        GLD16(e1, h0p + 1 * 32); GLD16(r1, h1p + 1 * 32);
        GLD16(e2, h0p + 2 * 32); GLD16(r2, h1p + 2 * 32);
        GLD16(e3, h0p + 3 * 32); GLD16(r3, h1p + 3 * 32);
        GLD16(e4, h0p + 4 * 32); GLD16(r4, h1p + 4 * 32);
        GLD16(e5, h0p + 5 * 32); GLD16(r5, h1p + 5 * 32);
        GLD16(e6, h0p + 6 * 32); GLD16(r6, h1p + 6 * 32);
        GLD16(e7, h0p + 7 * 32); GLD16(r7, h1p + 7 * 32);
#define L1W(j, s, wn) \
        { asm volatile("s_waitcnt vmcnt(" #wn ")" : "+v"(e##s), "+v"(r##s)); \
          bf16x8 bx = *(const bf16x8*)(&wlds[((j) * 32) * 16 + lane * 8]); \
          bf16x8 bh = *(const bf16x8*)(&wlds[((j) * 32 + 1024) * 16 + lane * 8]); \
          aX = __builtin_amdgcn_mfma_f32_16x16x32_bf16(e##s, bx, aX, 0, 0, 0); \
          aH = __builtin_amdgcn_mfma_f32_16x16x32_bf16(r##s, bh, aH, 0, 0, 0); }
#define L1WI(j, s) \
        { asm volatile("s_waitcnt vmcnt(14)" : "+v"(e##s), "+v"(r##s)); \
          bf16x8 bx = *(const bf16x8*)(&wlds[((j) * 32) * 16 + lane * 8]); \
          bf16x8 bh = *(const bf16x8*)(&wlds[((j) * 32 + 1024) * 16 + lane * 8]); \
          aX = __builtin_amdgcn_mfma_f32_16x16x32_bf16(e##s, bx, aX, 0, 0, 0); \
          aH = __builtin_amdgcn_mfma_f32_16x16x32_bf16(r##s, bh, aH, 0, 0, 0); \
          GLD16(e##s, h0p + ((j) + 8) * 32); \
          GLD16(r##s, h1p + ((j) + 8) * 32); }
        L1WI(0,0) L1WI(1,1) L1WI(2,2) L1WI(3,3) L1WI(4,4) L1WI(5,5) L1WI(6,6) L1WI(7,7)
        L1WI(8,0) L1WI(9,1) L1WI(10,2) L1WI(11,3) L1WI(12,4) L1WI(13,5) L1WI(14,6) L1WI(15,7)
        L1WI(16,0) L1WI(17,1) L1WI(18,2) L1WI(19,3) L1WI(20,4) L1WI(21,5) L1WI(22,6) L1WI(23,7)
        L1W(24,0,14) L1W(25,1,12) L1W(26,2,10) L1W(27,3,8)
        L1W(28,4,6)  L1W(29,5,4)  L1W(30,6,2)  L1W(31,7,0)
#undef L1W
#undef L1WI
      }

      unsigned short* hdst = h1s + (((size_t)(u & 1)) << 16);
      #pragma unroll
      for (int i = 0; i < 4; ++i) {
        const int r = crow + i;
        const float v = tanhf(aX[i] + aH[i] + biasv);
        const float w = __shfl_xor(v, 1);
        if (!(lane & 1)) {
          unsigned int pk = (unsigned int)f2bf(v) | ((unsigned int)f2bf(w) << 16);
          __hip_atomic_store((unsigned int*)(hdst + (((size_t)r) << 10) + ccol), pk,
                             __ATOMIC_RELAXED, __HIP_MEMORY_SCOPE_AGENT);
        }
        __builtin_nontemporal_store(v, &out[((((size_t)u << 6) + r) << 10) + ccol]);
        if (u == T_STEPS - 1) hfin[((size_t)(r * 2 + 1) << 10) + ccol] = v;
      }

      asm volatile("s_waitcnt vmcnt(0)" ::: "memory");
      __syncthreads();
      if (tid == 0)
        __hip_atomic_fetch_add(&ctr1[(wg & 7) << 5], 1, __ATOMIC_RELAXED, __HIP_MEMORY_SCOPE_AGENT);
    }
  }
}

extern "C" void kernel_launch(void* const* d_in, const int* in_sizes, int n_in,
                              void* d_out, int out_size, void* d_ws, size_t ws_size,
                              hipStream_t stream) {
  (void)in_sizes; (void)n_in; (void)out_size; (void)ws_size;
  const float* x   = (const float*)d_in[0];
  const float* h0  = (const float*)d_in[1];
  const float* Wih = (const float*)d_in[2];
  const float* bih = (const float*)d_in[3];
  const float* Whh = (const float*)d_in[4];
  const float* bhh = (const float*)d_in[5];
  float* out = (float*)d_out;
  char* ws = (char*)d_ws;

  unsigned short* xb  = (unsigned short*)(ws + OFF_XB);
  unsigned short* wts = (unsigned short*)(ws + OFF_W);
  unsigned short* h0s = (unsigned short*)(ws + OFF_H0);
  unsigned short* h1s = (unsigned short*)(ws + OFF_H1);
  float* bias = (float*)(ws + OFF_B);
  int* ctr = (int*)(ws + OFF_CTR);

  k_cvt_x<<<65536, 256, 0, stream>>>((const float4*)x, (ushort4*)xb);
  k_cvt_w<<<4096, 256, 0, stream>>>(Wih, Whh, (ushort4*)wts);
  k_init<<<512, 256, 0, stream>>>(h0, bih, bhh, h0s, h1s, bias, ctr);
  k_rnn<<<NBLK, 256, 0, stream>>>(xb, wts, h0s, h1s, bias, ctr, out);
}